// Round 4
// baseline (318.419 us; speedup 1.0000x reference)
//
#include <hip/hip_runtime.h>

// BackprojectDepth — R8: grid-stride flat sweep (mimic the fill's write topology).
//
// R5 (store flavor) and R7 (block lifetime / MLP) were both neutral: the kernel
// is pinned at ~124 us (~2.4 TB/s) under every blockIdx-partitioned layout.
// The invariant across all of them: ~8192 concurrent 4 KB write regions
// scattered over the whole 268 MB output (each block owns (b,row) and writes
// 4 plane-streams 2 MB apart) -> HBM open-row thrash / random L2 evictions.
// The poison fill hits 6.4 TB/s on the SAME buffer with the opposite
// topology: a grid-stride sweep where the whole GPU writes one contiguous
// ~8 MB window that slides sequentially.
//
// R8 adopts that topology. 2048 blocks x 256 threads x vf4 = 2^21 floats
// = exactly one batch (4*H*W), so a thread's (c, n, x, y) are FIXED and only
// b advances per iteration: invK/dxy loads are loop-uniform (s_load), c is
// wave-uniform (readfirstlane -> scalar row fetch). Whole grid co-resident
// (32 waves/CU). Depth plane b is read by the c=0/1/2 waves within ~us of
// each other -> L2/L3 hits; c=3 waves store constant ones, no loads.

#define BB 32
#define HH 512
#define WW 1024
#define HWN (HH * WW)        // 524288 = 2^19

typedef float vf4 __attribute__((ext_vector_type(4)));

__global__ __launch_bounds__(256) void backproject_kernel(
    const float* __restrict__ depth,   // [B, 1, H, W]
    const float* __restrict__ invK,    // [B, 4, 4]
    const int*   __restrict__ dxy,     // [B, 2]
    float*       __restrict__ out)     // [B, 4, H*W]
{
    const int gid = blockIdx.x * 256 + threadIdx.x;   // 0 .. 524287
    const int o   = gid * 4;                          // float offset inside one batch slab
    const int c   = o >> 19;                          // plane 0..3 (wave-uniform in value)
    const int n   = o & (HWN - 1);                    // pixel index of this vf4
    const float xf = (float)(n & (WW - 1));
    const float yf = (float)(n >> 10);

    const vf4 ones = {1.f, 1.f, 1.f, 1.f};

    if (c == 3) {
        // Ones plane: pure store stream, no loads. Wave-uniform branch.
        float* optr = out + o;
        #pragma unroll 4
        for (int b = 0; b < BB; ++b, optr += 4 * HWN)
            *(vf4*)optr = ones;
        return;
    }

    // c is uniform across the wave (a wave spans 256 consecutive floats,
    // planes are 2^19 floats) — hoist to SGPR so invK row loads are scalar.
    const int cs = __builtin_amdgcn_readfirstlane(c);

    const float* dptr = depth + n;
    float*       optr = out + o;

    #pragma unroll 2
    for (int b = 0; b < BB; ++b, dptr += HWN, optr += 4 * HWN) {
        // Loop-uniform scalar loads (b, cs both uniform)
        const float a0 = invK[b * 16 + cs * 4 + 0];
        const float a1 = invK[b * 16 + cs * 4 + 1];
        const float a2 = invK[b * 16 + cs * 4 + 2];
        const float dx = (float)dxy[b * 2 + 0];
        const float dy = (float)dxy[b * 2 + 1];

        const float x0 = xf + dx;
        const float cc = __builtin_fmaf(a1, yf + dy, a2);

        const vf4 d = *(const vf4*)dptr;

        vf4 r;
        r.x = d.x * __builtin_fmaf(a0, x0 + 0.f, cc);
        r.y = d.y * __builtin_fmaf(a0, x0 + 1.f, cc);
        r.z = d.z * __builtin_fmaf(a0, x0 + 2.f, cc);
        r.w = d.w * __builtin_fmaf(a0, x0 + 3.f, cc);

        *(vf4*)optr = r;
    }
}

extern "C" void kernel_launch(void* const* d_in, const int* in_sizes, int n_in,
                              void* d_out, int out_size, void* d_ws, size_t ws_size,
                              hipStream_t stream) {
    const float* depth = (const float*)d_in[0];
    const float* invK  = (const float*)d_in[1];
    const int*   dxy   = (const int*)d_in[2];
    float*       out   = (float*)d_out;

    // 2048 blocks: whole grid co-resident (8 blocks/CU = 32 waves/CU),
    // one sliding 8 MB write window over the 268 MB output.
    backproject_kernel<<<dim3(2048), 256, 0, stream>>>(depth, invK, dxy, out);
}